// Round 11
// baseline (115.127 us; speedup 1.0000x reference)
//
#include <hip/hip_runtime.h>
#include <math.h>

#define DD 384
#define HD 1024
#define CD 256
#define NS 765        // 2*DD-1 shifts
#define NITER 4
#define NROWS 256     // B*T
#define TEMPER_F 10.0f
#define EPSF 1e-6f
#define CUTF 1e-10f

typedef unsigned long long u64;
typedef unsigned int u32;

// monotone float->uint (ascending)
__device__ __forceinline__ u32 flipf(float f) {
    u32 u = __float_as_uint(f);
    return u ^ ((u32)((int)u >> 31) | 0x80000000u);
}
// inverse, where s = ~flip(v)
__device__ __forceinline__ float unflipf(u32 s) {
    u32 fl = ~s;
    u32 u = (fl & 0x80000000u) ? (fl ^ 0x80000000u) : ~fl;
    return __uint_as_float(u);
}
__device__ __forceinline__ u64 shflx64(u64 v, int m) {
    int lo = __shfl_xor((int)(u32)v, m, 64);
    int hi = __shfl_xor((int)(u32)(v >> 32), m, 64);
    return ((u64)(u32)hi << 32) | (u32)lo;
}

// ---------------- 1) prep: per-row theta / attn / x_ele + y-count ----------------
// 384 threads = 6 waves (one d per thread in all elementwise phases).
__global__ __launch_bounds__(384) void prep_kernel(
    const float* __restrict__ x, const float* __restrict__ y,
    float* __restrict__ xe_g, int* __restrict__ ycnt)
{
    const int row  = blockIdx.x;
    const int tid  = threadIdx.x;
    const int lane = tid & 63;
    const int wid  = tid >> 6;

    __shared__ __align__(16) float xpad[1152];
    __shared__ __align__(16) float yr[DD];
    __shared__ float xa[DD];
    __shared__ float wred[8];
    __shared__ int   wredi[8];
    __shared__ float wredn[8];
    __shared__ float s_sc[4];
    __shared__ int   s_theta;

    const float* xrow = x + row * DD;
    const float* yrow = y + row * DD;

    for (int i = tid; i < 1152; i += 384)
        xpad[i] = (i >= DD - 1 && i < 2 * DD - 1) ? xrow[i - (DD - 1)] : 0.f;
    yr[tid] = yrow[tid];
    __syncthreads();

    // qn = ||y||  (+ y-count folded in)
    {
        float p = yr[tid] * yr[tid];
        int   c = (yr[tid] != 0.f) ? 1 : 0;
        for (int o = 32; o; o >>= 1) {
            p += __shfl_xor(p, o, 64);
            c += __shfl_xor(c, o, 64);
        }
        if (lane == 0) { wred[wid] = p; wredi[wid] = c; }
    }
    __syncthreads();
    if (tid == 0) {
        float s = 0.f; int c = 0;
        for (int w = 0; w < 6; ++w) { s += wred[w]; c += wredi[w]; }
        s_sc[0] = sqrtf(s);
        ycnt[row] = c;
    }
    __syncthreads();
    const float qn = s_sc[0];

    // sim argmax: threads 0..191 (waves 0..2), 4 consecutive shifts each
    float bv = -INFINITY; int bs = 0x7fffffff; float bn = 0.f;
    if (tid < 192) {
        const float4* xp4 = (const float4*)xpad;
        const float4* yp4 = (const float4*)yr;
        float4 A = xp4[tid];
        const float f0 = A.x * A.x, f1 = A.y * A.y, f2 = A.z * A.z;
        float d0 = 0.f, d1 = 0.f, d2 = 0.f, d3 = 0.f, n0 = 0.f;
#pragma unroll 4
        for (int jc = 0; jc < 96; ++jc) {
            float4 B = xp4[tid + jc + 1];
            float4 Y = yp4[jc];
            d0 += A.x * Y.x; d0 += A.y * Y.y; d0 += A.z * Y.z; d0 += A.w * Y.w;
            d1 += A.y * Y.x; d1 += A.z * Y.y; d1 += A.w * Y.z; d1 += B.x * Y.w;
            d2 += A.z * Y.x; d2 += A.w * Y.y; d2 += B.x * Y.z; d2 += B.y * Y.w;
            d3 += A.w * Y.x; d3 += B.x * Y.y; d3 += B.y * Y.z; d3 += B.z * Y.w;
            n0 += A.x * A.x; n0 += A.y * A.y; n0 += A.z * A.z; n0 += A.w * A.w;
            A = B;
        }
        const float n1 = n0 - f0 + A.x * A.x;
        const float n2 = n1 - f1 + A.y * A.y;
        const float n3 = n2 - f2 + A.z * A.z;
        const int s0 = 4 * tid;
        float sim0 = d0 / (qn * sqrtf(n0) + EPSF);
        float sim1 = d1 / (qn * sqrtf(n1) + EPSF);
        float sim2 = d2 / (qn * sqrtf(n2) + EPSF);
        float sim3 = d3 / (qn * sqrtf(n3) + EPSF);
        bv = sim0; bs = s0; bn = n0;
        if (s0 + 1 < NS && sim1 > bv) { bv = sim1; bs = s0 + 1; bn = n1; }
        if (s0 + 2 < NS && sim2 > bv) { bv = sim2; bs = s0 + 2; bn = n2; }
        if (s0 + 3 < NS && sim3 > bv) { bv = sim3; bs = s0 + 3; bn = n3; }
    }
    for (int o = 32; o; o >>= 1) {
        float v2 = __shfl_xor(bv, o, 64);
        int   i2 = __shfl_xor(bs, o, 64);
        float n2 = __shfl_xor(bn, o, 64);
        if (v2 > bv || (v2 == bv && i2 < bs)) { bv = v2; bs = i2; bn = n2; }
    }
    if (lane == 0) { wred[wid] = bv; wredi[wid] = bs; wredn[wid] = bn; }
    __syncthreads();
    if (tid == 0) {
        float v = wred[0]; int b = wredi[0]; float nn = wredn[0];
        for (int w = 1; w < 6; ++w)
            if (wred[w] > v || (wred[w] == v && wredi[w] < b)) {
                v = wred[w]; b = wredi[w]; nn = wredn[w];
            }
        s_theta = b;
        s_sc[1] = sqrtf(nn) * qn + EPSF;   // dn from carried nrm(theta)
    }
    __syncthreads();
    const int theta = s_theta;
    const float dn = s_sc[1];

    // softmax((x_opt*y/dn)/T); x_attn
    const float xo = xpad[theta + tid];
    const float z = (xo * yr[tid] / dn) / TEMPER_F;
    {
        float m = z;
        for (int o = 32; o; o >>= 1) { float w2 = __shfl_xor(m, o, 64); if (w2 > m) m = w2; }
        if (lane == 0) wred[wid] = m;
    }
    __syncthreads();
    if (tid == 0) {
        float m = wred[0];
        for (int w = 1; w < 6; ++w) if (wred[w] > m) m = wred[w];
        s_sc[2] = m;
    }
    __syncthreads();
    const float ez = expf(z - s_sc[2]);
    {
        float p = ez;
        for (int o = 32; o; o >>= 1) p += __shfl_xor(p, o, 64);
        if (lane == 0) wred[wid] = p;
    }
    __syncthreads();
    if (tid == 0) {
        float s = 0.f;
        for (int w = 0; w < 6; ++w) s += wred[w];
        s_sc[3] = s;
    }
    __syncthreads();
    xa[tid] = xo * (ez / s_sc[3]);
    __syncthreads();
    {
        int sj = tid - (theta - (DD - 1));
        xe_g[row * DD + tid] = (sj >= 0 && sj < DD) ? xa[sj] : 0.f;
    }
}

// ---------------- 2) encoder GEMM: h = xe @ Wenc + benc ----------------
// grid 1024 = 32 row-tiles(8 rows) x 32 col-tiles(32 cols); 256 thr; 4 blocks/CU.
// K split 4x across waves (96-deep, unroll 8 -> 12 latency exposures), LDS reduce.
__global__ __launch_bounds__(256) void enc_gemm(
    const float* __restrict__ xe_g, const float* __restrict__ Wenc,
    const float* __restrict__ benc, float* __restrict__ h_g)
{
    const int rt = blockIdx.x >> 5;        // 0..31
    const int ct = blockIdx.x & 31;        // 0..31
    const int tid = threadIdx.x;
    __shared__ float A[8][388];            // +4 pad: 384%32==0 would 8-way conflict
    __shared__ __align__(16) float4 part[3][64];

    {
        const float4* src = (const float4*)(xe_g + (size_t)rt * 8 * DD);
        for (int i = tid; i < 768; i += 256) {
            float4 v = src[i];
            int r = i / 96, c = (i - r * 96) * 4;
            A[r][c] = v.x; A[r][c+1] = v.y; A[r][c+2] = v.z; A[r][c+3] = v.w;
        }
    }
    __syncthreads();

    const int cq = tid & 7;                // col quad 0..7
    const int r  = (tid >> 3) & 7;         // row 0..7
    const int ks = tid >> 6;               // K-split = wave id 0..3
    const int col = ct * 32 + cq * 4;
    const float* wp = Wenc + (size_t)(ks * 96) * HD + col;
    const float* ar = &A[r][ks * 96];
    float4 acc = make_float4(0.f, 0.f, 0.f, 0.f);
#pragma unroll 8
    for (int j = 0; j < 96; ++j) {
        float a = ar[j];                   // 8 distinct banks, 8-lane broadcast: free
        float4 w = *(const float4*)(wp + (size_t)j * HD);
        acc.x += a * w.x; acc.y += a * w.y;
        acc.z += a * w.z; acc.w += a * w.w;
    }
    if (ks) part[ks - 1][tid & 63] = acc;
    __syncthreads();
    if (ks == 0) {
        float4 p1 = part[0][tid], p2 = part[1][tid], p3 = part[2][tid];
        float4 bb = *(const float4*)(benc + col);
        acc.x += p1.x + p2.x + p3.x + bb.x;
        acc.y += p1.y + p2.y + p3.y + bb.y;
        acc.z += p1.z + p2.z + p3.z + bb.z;
        acc.w += p1.w + p2.w + p3.w + bb.w;
        *(float4*)(h_g + (size_t)(rt * 8 + r) * HD + col) = acc;
    }
}

// ---------------- 3) sort + decode per row (R8's proven phases) ----------------
__global__ __launch_bounds__(512) void sortdec_kernel(
    const float* __restrict__ h_g,
    const float* __restrict__ Wdec, const float* __restrict__ bdec,
    const float* __restrict__ x, const float* __restrict__ y,
    float* __restrict__ out_xdis, float* __restrict__ lossp)
{
    const int row  = blockIdx.x;
    const int tid  = threadIdx.x;
    const int lane = tid & 63;

    __shared__ __align__(16) u64   skey[HD];   // LDS rounds (j>=128) only
    __shared__ __align__(16) uint2 dec2[HD];
    __shared__ int   s_fb;
    __shared__ float loss4[NITER];

    // keys from coalesced float2 global reads
    float2 hh = *(const float2*)(h_g + (size_t)row * HD + 2 * tid);
    u64 e0 = ((u64)(~flipf(hh.x)) << 32) | (u32)(2 * tid);
    u64 e1 = ((u64)(~flipf(hh.y)) << 32) | (u32)(2 * tid + 1);
    if (tid == 0) s_fb = HD;
    if (tid < NITER) loss4[tid] = 0.f;
    __syncthreads();

    // register bitonic: thread owns 2t, 2t+1; ascending u64 == (desc h, asc idx)
    for (int k = 2; k <= HD; k <<= 1) {
        const bool up = ((2 * tid) & k) == 0;
        for (int j = k >> 1; j > 0; j >>= 1) {
            if (j == 1) {
                bool sw = up ? (e0 > e1) : (e0 < e1);
                if (sw) { u64 t2 = e0; e0 = e1; e1 = t2; }
            } else if (j <= 64) {
                const int m = j >> 1;
                u64 p0 = shflx64(e0, m);
                u64 p1 = shflx64(e1, m);
                const bool takeMin = (((tid & m) == 0) == up);
                e0 = takeMin ? (e0 < p0 ? e0 : p0) : (e0 > p0 ? e0 : p0);
                e1 = takeMin ? (e1 < p1 ? e1 : p1) : (e1 > p1 ? e1 : p1);
            } else {                           // j in {128,256,512}: via LDS
                __syncthreads();
                skey[2 * tid]     = e0;
                skey[2 * tid + 1] = e1;
                __syncthreads();
                const int tp = tid ^ (j >> 1);
                u64 p0 = skey[2 * tp];
                u64 p1 = skey[2 * tp + 1];
                const bool takeMin = (((tid & (j >> 1)) == 0) == up);
                e0 = takeMin ? (e0 < p0 ? e0 : p0) : (e0 > p0 ? e0 : p0);
                e1 = takeMin ? (e1 < p1 ? e1 : p1) : (e1 > p1 ? e1 : p1);
            }
        }
    }

    // unpack + first position with v <= CUTF
    {
        float v0 = unflipf((u32)(e0 >> 32));
        float v1 = unflipf((u32)(e1 >> 32));
        dec2[2 * tid]     = make_uint2(__float_as_uint(v0), ((u32)e0) * DD);
        dec2[2 * tid + 1] = make_uint2(__float_as_uint(v1), ((u32)e1) * DD);
        int fbloc = HD;
        if (!(v1 > CUTF)) fbloc = 2 * tid + 1;
        if (!(v0 > CUTF)) fbloc = 2 * tid;
        for (int o = 32; o; o >>= 1) { int t2 = __shfl_xor(fbloc, o, 64); if (t2 < fbloc) fbloc = t2; }
        if (lane == 0) atomicMin(&s_fb, fbloc);
    }
    __syncthreads();
    const int fb = s_fb;

    // decode: 4 groups of 128 threads (k wave-uniform), 4 d-cols/thread, unroll 8
    {
        const int k = tid >> 7;
        const int g = tid & 127;
        const bool active = (g < 96);
        int n = 0;
        if (active) {
            n = (k == 0) ? CD : fb - k * CD;
            if (n < 0) n = 0; if (n > CD) n = CD;
        }
        float4 oacc = make_float4(0.f, 0.f, 0.f, 0.f);
        if (active) oacc = *(const float4*)&bdec[4 * g];
        const float* wd = Wdec + 4 * g;
        const int base = k * CD;
        int r = 0;
        for (; r + 8 <= n; r += 8) {
#pragma unroll
            for (int q = 0; q < 8; q += 2) {
                uint4 dv = *(const uint4*)&dec2[base + r + q];
                float v0 = __uint_as_float(dv.x);
                float4 w0 = *(const float4*)(wd + dv.y);
                float v1 = __uint_as_float(dv.z);
                float4 w1 = *(const float4*)(wd + dv.w);
                oacc.x += v0 * w0.x; oacc.y += v0 * w0.y;
                oacc.z += v0 * w0.z; oacc.w += v0 * w0.w;
                oacc.x += v1 * w1.x; oacc.y += v1 * w1.y;
                oacc.z += v1 * w1.z; oacc.w += v1 * w1.w;
            }
        }
        for (; r < n; ++r) {
            uint2 dv = dec2[base + r];
            float v0 = __uint_as_float(dv.x);
            float4 w0 = *(const float4*)(wd + dv.y);
            oacc.x += v0 * w0.x; oacc.y += v0 * w0.y;
            oacc.z += v0 * w0.z; oacc.w += v0 * w0.w;
        }
        float l = 0.f;
        if (active) {
            *(float4*)&out_xdis[((size_t)k * NROWS + row) * DD + 4 * g] = oacc;
            float4 xv = *(const float4*)&x[row * DD + 4 * g];
            float4 yv = *(const float4*)&y[row * DD + 4 * g];
            float e;
            e = oacc.x - xv.x; if (yv.x != 0.f) l += e * e;
            e = oacc.y - xv.y; if (yv.y != 0.f) l += e * e;
            e = oacc.z - xv.z; if (yv.z != 0.f) l += e * e;
            e = oacc.w - xv.w; if (yv.w != 0.f) l += e * e;
        }
        for (int o = 32; o; o >>= 1) l += __shfl_xor(l, o, 64);
        if (lane == 0) atomicAdd(&loss4[k], l);
    }
    __syncthreads();
    if (tid < NITER) lossp[row * NITER + tid] = loss4[tid];
}

// ---------------- 4) finalize: losses[k] = sum lossp / sum ycnt ----------------
__global__ __launch_bounds__(256) void finalize2(
    const float* __restrict__ lossp, const int* __restrict__ ycnt,
    float* __restrict__ losses)
{
    const int tid = threadIdx.x, lane = tid & 63, w = tid >> 6;
    __shared__ int ctot[4];
    int c = ycnt[tid];
    for (int o = 32; o; o >>= 1) c += __shfl_xor(c, o, 64);
    if (lane == 0) ctot[w] = c;
    __syncthreads();
    const int total = ctot[0] + ctot[1] + ctot[2] + ctot[3];
    float s = lossp[lane * NITER + w] + lossp[(lane + 64) * NITER + w]
            + lossp[(lane + 128) * NITER + w] + lossp[(lane + 192) * NITER + w];
    for (int o = 32; o; o >>= 1) s += __shfl_xor(s, o, 64);
    if (lane == 0) losses[w] = s / (float)total;
}

extern "C" void kernel_launch(void* const* d_in, const int* in_sizes, int n_in,
                              void* d_out, int out_size, void* d_ws, size_t ws_size,
                              hipStream_t stream) {
    const float* x    = (const float*)d_in[0];
    const float* y    = (const float*)d_in[1];
    const float* Wenc = (const float*)d_in[2];
    const float* benc = (const float*)d_in[3];
    const float* Wdec = (const float*)d_in[4];
    const float* bdec = (const float*)d_in[5];

    float* out  = (float*)d_out;
    float* loss = out + (out_size - NITER);

    // workspace (all regions fully written before read each launch)
    int*   ycnt  = (int*)d_ws;                           // 256 ints
    float* lossp = (float*)(ycnt + NROWS);               // 1024 floats
    float* xe_g  = lossp + NROWS * NITER;                // 256*384 (16B-aligned)
    float* h_g   = xe_g + (size_t)NROWS * DD;            // 256*1024

    prep_kernel<<<NROWS, 384, 0, stream>>>(x, y, xe_g, ycnt);
    enc_gemm<<<1024, 256, 0, stream>>>(xe_g, Wenc, benc, h_g);
    sortdec_kernel<<<NROWS, 512, 0, stream>>>(h_g, Wdec, bdec, x, y, out, lossp);
    finalize2<<<1, 256, 0, stream>>>(lossp, ycnt, loss);
}

// Round 12
// 111.265 us; speedup vs baseline: 1.0347x; 1.0347x over previous
//
#include <hip/hip_runtime.h>
#include <math.h>

#define DD 384
#define HD 1024
#define CD 256
#define NS 765        // 2*DD-1 shifts
#define NITER 4
#define NROWS 256     // B*T
#define TEMPER_F 10.0f
#define EPSF 1e-6f
#define CUTF 1e-10f

typedef unsigned long long u64;
typedef unsigned int u32;

// monotone float->uint (ascending)
__device__ __forceinline__ u32 flipf(float f) {
    u32 u = __float_as_uint(f);
    return u ^ ((u32)((int)u >> 31) | 0x80000000u);
}
// inverse, where s = ~flip(v)
__device__ __forceinline__ float unflipf(u32 s) {
    u32 fl = ~s;
    u32 u = (fl & 0x80000000u) ? (fl ^ 0x80000000u) : ~fl;
    return __uint_as_float(u);
}
__device__ __forceinline__ u64 shflx64(u64 v, int m) {
    int lo = __shfl_xor((int)(u32)v, m, 64);
    int hi = __shfl_xor((int)(u32)(v >> 32), m, 64);
    return ((u64)(u32)hi << 32) | (u32)lo;
}
// fp32 -> bf16 (RTNE), packed pair (lo element in low 16 bits)
__device__ __forceinline__ u32 bf16r(float f) {
    u32 u = __float_as_uint(f);
    return (u + 0x7FFFu + ((u >> 16) & 1u)) >> 16;
}
__device__ __forceinline__ u32 pack2(float a, float b) {
    return bf16r(a) | (bf16r(b) << 16);
}
// unpack: low half / high half of a packed pair
__device__ __forceinline__ float blo(u32 p) { return __uint_as_float(p << 16); }
__device__ __forceinline__ float bhi(u32 p) { return __uint_as_float(p & 0xFFFF0000u); }

// ---- 0) convert weights to packed bf16 in d_ws (per launch; d_ws is re-poisoned) ----
// Precision rationale: h ~ N(0, 2e-3); Wenc-bf16 perturbs h by ~4e-6 abs. Rank flips
// swap near-equal h values (cost <= h*|dWdec_row| ~ 2e-4); fb shifts only move
// |h|<=4e-6 terms. All << 2e-2 threshold. sim/theta path stays fp32 (gaps too tight).
__global__ __launch_bounds__(256) void convert_kernel(
    const float* __restrict__ We, const float* __restrict__ Wd,
    uint2* __restrict__ we16, uint2* __restrict__ wd16)
{
    const int t = blockIdx.x * 256 + threadIdx.x;      // 65536 threads
    for (int i = t; i < (DD * HD) / 4; i += 65536) {   // 98304 float4 groups
        float4 v = ((const float4*)We)[i];
        we16[i] = make_uint2(pack2(v.x, v.y), pack2(v.z, v.w));
    }
    for (int i = t; i < (HD * DD) / 4; i += 65536) {
        float4 v = ((const float4*)Wd)[i];
        wd16[i] = make_uint2(pack2(v.x, v.y), pack2(v.z, v.w));
    }
}

// One block per row: prep -> encoder(bf16 W) -> register-bitonic sort -> decode(bf16 W).
__global__ __launch_bounds__(512) void fused_kernel(
    const float* __restrict__ x, const float* __restrict__ y,
    const u32* __restrict__ wenc16, const float* __restrict__ benc,
    const u32* __restrict__ wdec16, const float* __restrict__ bdec,
    float* __restrict__ out_xdis, float* __restrict__ lossp,
    int* __restrict__ ycnt)
{
    const int row  = blockIdx.x;
    const int tid  = threadIdx.x;
    const int lane = tid & 63;
    const int wid  = tid >> 6;

    __shared__ __align__(16) float xpad[1152];    // xfull(t), zero-padded
    __shared__ __align__(16) float yr[DD];
    __shared__ float xa[DD];
    __shared__ __align__(16) float xe_s[DD];
    __shared__ __align__(16) float hpart[HD];     // split-K partial, then final h
    __shared__ __align__(16) u64   skey[HD];      // sort LDS rounds (j>=128) only
    __shared__ __align__(16) uint2 dec2[HD];      // {bits(v), idx*192 (u32 units)}
    __shared__ float wred[8];
    __shared__ int   wredi[8];
    __shared__ float wredn[8];
    __shared__ float s_sc[4];                     // qn, dn, mx, sum
    __shared__ int   s_theta, s_fb;
    __shared__ float loss4[NITER];

    const float* xrow = x + row * DD;
    const float* yrow = y + row * DD;

    // xfull(t) = x[t-383] for t in [383,767), else 0
    for (int i = tid; i < 1152; i += 512)
        xpad[i] = (i >= DD - 1 && i < 2 * DD - 1) ? xrow[i - (DD - 1)] : 0.f;
    if (tid < DD) yr[tid] = yrow[tid];
    __syncthreads();

    // ---- qn = ||y||  (+ y-count folded into the same round) ----
    if (tid < DD) {
        float p = yr[tid] * yr[tid];
        int   c = (yr[tid] != 0.f) ? 1 : 0;
        for (int o = 32; o; o >>= 1) {
            p += __shfl_xor(p, o, 64);
            c += __shfl_xor(c, o, 64);
        }
        if (lane == 0) { wred[wid] = p; wredi[wid] = c; }
    }
    __syncthreads();
    if (tid == 0) {
        float s = 0.f; int c = 0;
        for (int w = 0; w < 6; ++w) { s += wred[w]; c += wredi[w]; }
        s_sc[0] = sqrtf(s);
        ycnt[row] = c;
    }
    __syncthreads();
    const float qn = s_sc[0];

    // ---- sim argmax: threads 0..191, 4 consecutive shifts each, sliding window ----
    float bv = -INFINITY; int bs = 0x7fffffff; float bn = 0.f;
    if (tid < 192) {
        const float4* xp4 = (const float4*)xpad;
        const float4* yp4 = (const float4*)yr;
        float4 A = xp4[tid];
        const float f0 = A.x * A.x, f1 = A.y * A.y, f2 = A.z * A.z;
        float d0 = 0.f, d1 = 0.f, d2 = 0.f, d3 = 0.f, n0 = 0.f;
#pragma unroll 4
        for (int jc = 0; jc < 96; ++jc) {
            float4 B = xp4[tid + jc + 1];
            float4 Y = yp4[jc];
            d0 += A.x * Y.x; d0 += A.y * Y.y; d0 += A.z * Y.z; d0 += A.w * Y.w;
            d1 += A.y * Y.x; d1 += A.z * Y.y; d1 += A.w * Y.z; d1 += B.x * Y.w;
            d2 += A.z * Y.x; d2 += A.w * Y.y; d2 += B.x * Y.z; d2 += B.y * Y.w;
            d3 += A.w * Y.x; d3 += B.x * Y.y; d3 += B.y * Y.z; d3 += B.z * Y.w;
            n0 += A.x * A.x; n0 += A.y * A.y; n0 += A.z * A.z; n0 += A.w * A.w;
            A = B;
        }
        const float n1 = n0 - f0 + A.x * A.x;
        const float n2 = n1 - f1 + A.y * A.y;
        const float n3 = n2 - f2 + A.z * A.z;
        const int s0 = 4 * tid;
        float sim0 = d0 / (qn * sqrtf(n0) + EPSF);
        float sim1 = d1 / (qn * sqrtf(n1) + EPSF);
        float sim2 = d2 / (qn * sqrtf(n2) + EPSF);
        float sim3 = d3 / (qn * sqrtf(n3) + EPSF);
        bv = sim0; bs = s0; bn = n0;
        if (s0 + 1 < NS && sim1 > bv) { bv = sim1; bs = s0 + 1; bn = n1; }
        if (s0 + 2 < NS && sim2 > bv) { bv = sim2; bs = s0 + 2; bn = n2; }
        if (s0 + 3 < NS && sim3 > bv) { bv = sim3; bs = s0 + 3; bn = n3; }
    }
    for (int o = 32; o; o >>= 1) {
        float v2 = __shfl_xor(bv, o, 64);
        int   i2 = __shfl_xor(bs, o, 64);
        float n2 = __shfl_xor(bn, o, 64);
        if (v2 > bv || (v2 == bv && i2 < bs)) { bv = v2; bs = i2; bn = n2; }
    }
    if (lane == 0) { wred[wid] = bv; wredi[wid] = bs; wredn[wid] = bn; }
    __syncthreads();
    if (tid == 0) {
        float v = wred[0]; int b = wredi[0]; float nn = wredn[0];
        for (int w = 1; w < 8; ++w)
            if (wred[w] > v || (wred[w] == v && wredi[w] < b)) {
                v = wred[w]; b = wredi[w]; nn = wredn[w];
            }
        s_theta = b;
        s_sc[1] = sqrtf(nn) * qn + EPSF;      // dn from carried nrm(theta)
    }
    __syncthreads();
    const int theta = s_theta;
    const float dn = s_sc[1];

    // ---- softmax((x_opt*y/dn)/T); x_attn ----
    float xo = 0.f, z = 0.f;
    if (tid < DD) {
        xo = xpad[theta + tid];
        z = (xo * yr[tid] / dn) / TEMPER_F;
        float m = z;
        for (int o = 32; o; o >>= 1) { float w2 = __shfl_xor(m, o, 64); if (w2 > m) m = w2; }
        if (lane == 0) wred[wid] = m;
    }
    __syncthreads();
    if (tid == 0) {
        float m = wred[0];
        for (int w = 1; w < 6; ++w) if (wred[w] > m) m = wred[w];
        s_sc[2] = m;
    }
    __syncthreads();
    float ez = 0.f;
    if (tid < DD) {
        ez = expf(z - s_sc[2]);
        float p = ez;
        for (int o = 32; o; o >>= 1) p += __shfl_xor(p, o, 64);
        if (lane == 0) wred[wid] = p;
    }
    __syncthreads();
    if (tid == 0) {
        float s = 0.f;
        for (int w = 0; w < 6; ++w) s += wred[w];
        s_sc[3] = s;
    }
    __syncthreads();
    if (tid < DD) xa[tid] = xo * (ez / s_sc[3]);
    __syncthreads();
    if (tid < DD) {
        int sj = tid - (theta - (DD - 1));
        xe_s[tid] = (sj >= 0 && sj < DD) ? xa[sj] : 0.f;
    }
    __syncthreads();

    // ---- encoder: split-K GEMV on bf16 Wenc (8B/lane loads, fp32 FMA) ----
    const int c4 = tid & 255;
    const int jh = tid >> 8;
    float4 acc = make_float4(0.f, 0.f, 0.f, 0.f);
    {
        // u32 units: (j*HD + 4*c4)/2 = j*512 + 2*c4
        const u32* wbase = wenc16 + (size_t)(jh * 192) * 512 + 2 * c4;
        const float* xb = xe_s + jh * 192;
#pragma unroll 8
        for (int j = 0; j < 192; ++j) {
            float xv = xb[j];                 // broadcast
            uint2 wv = *(const uint2*)(wbase + (size_t)j * 512);
            acc.x += xv * blo(wv.x); acc.y += xv * bhi(wv.x);
            acc.z += xv * blo(wv.y); acc.w += xv * bhi(wv.y);
        }
    }
    if (jh == 1) *(float4*)&hpart[4 * c4] = acc;
    if (tid == 0) s_fb = HD;
    if (tid < NITER) loss4[tid] = 0.f;
    __syncthreads();
    if (jh == 0) {
        // same thread reads and rewrites its own slot: in-place final h
        float4 hp = *(const float4*)&hpart[4 * c4];
        float4 bb = *(const float4*)&benc[4 * c4];
        hp.x += acc.x + bb.x;
        hp.y += acc.y + bb.y;
        hp.z += acc.z + bb.z;
        hp.w += acc.w + bb.w;
        *(float4*)&hpart[4 * c4] = hp;
    }
    __syncthreads();

    // ---- build keys from contiguous float2 reads ----
    float2 hh = *(const float2*)&hpart[2 * tid];
    u64 e0 = ((u64)(~flipf(hh.x)) << 32) | (u32)(2 * tid);
    u64 e1 = ((u64)(~flipf(hh.y)) << 32) | (u32)(2 * tid + 1);

    // ---- register bitonic sort: thread t owns positions 2t, 2t+1 ----
    for (int k = 2; k <= HD; k <<= 1) {
        const bool up = ((2 * tid) & k) == 0;
        for (int j = k >> 1; j > 0; j >>= 1) {
            if (j == 1) {
                bool sw = up ? (e0 > e1) : (e0 < e1);
                if (sw) { u64 t2 = e0; e0 = e1; e1 = t2; }
            } else if (j <= 64) {
                const int m = j >> 1;          // lane xor mask 1..32
                u64 p0 = shflx64(e0, m);
                u64 p1 = shflx64(e1, m);
                const bool takeMin = (((tid & m) == 0) == up);
                e0 = takeMin ? (e0 < p0 ? e0 : p0) : (e0 > p0 ? e0 : p0);
                e1 = takeMin ? (e1 < p1 ? e1 : p1) : (e1 > p1 ? e1 : p1);
            } else {                           // j in {128,256,512}: via LDS
                __syncthreads();               // WAR protection
                skey[2 * tid]     = e0;
                skey[2 * tid + 1] = e1;
                __syncthreads();
                const int tp = tid ^ (j >> 1);
                u64 p0 = skey[2 * tp];
                u64 p1 = skey[2 * tp + 1];
                const bool takeMin = (((tid & (j >> 1)) == 0) == up);
                e0 = takeMin ? (e0 < p0 ? e0 : p0) : (e0 > p0 ? e0 : p0);
                e1 = takeMin ? (e1 < p1 ? e1 : p1) : (e1 > p1 ? e1 : p1);
            }
        }
    }

    // ---- unpack from registers + first position with v <= CUTF ----
    {
        float v0 = unflipf((u32)(e0 >> 32));
        float v1 = unflipf((u32)(e1 >> 32));
        dec2[2 * tid]     = make_uint2(__float_as_uint(v0), ((u32)e0) * 192);
        dec2[2 * tid + 1] = make_uint2(__float_as_uint(v1), ((u32)e1) * 192);
        int fbloc = HD;
        if (!(v1 > CUTF)) fbloc = 2 * tid + 1;
        if (!(v0 > CUTF)) fbloc = 2 * tid;
        for (int o = 32; o; o >>= 1) { int t2 = __shfl_xor(fbloc, o, 64); if (t2 < fbloc) fbloc = t2; }
        if (lane == 0) atomicMin(&s_fb, fbloc);
    }
    __syncthreads();
    const int fb = s_fb;

    // ---- decode: 4 groups of 128 threads (k wave-uniform), 4 d-cols/thread,
    //      bf16 Wdec gather (8B/lane), unroll 8 ----
    {
        const int k = tid >> 7;
        const int g = tid & 127;
        const bool active = (g < 96);
        int n = 0;
        if (active) {
            n = (k == 0) ? CD : fb - k * CD;
            if (n < 0) n = 0; if (n > CD) n = CD;
        }
        float4 oacc = make_float4(0.f, 0.f, 0.f, 0.f);
        if (active) oacc = *(const float4*)&bdec[4 * g];
        const u32* wd = wdec16 + 2 * g;       // u32 units: col offset 4g ushorts
        const int base = k * CD;
        int r = 0;
        for (; r + 8 <= n; r += 8) {
#pragma unroll
            for (int q = 0; q < 8; q += 2) {
                uint4 dv = *(const uint4*)&dec2[base + r + q];   // 2 entries
                float v0 = __uint_as_float(dv.x);
                uint2 w0 = *(const uint2*)(wd + dv.y);
                float v1 = __uint_as_float(dv.z);
                uint2 w1 = *(const uint2*)(wd + dv.w);
                oacc.x += v0 * blo(w0.x); oacc.y += v0 * bhi(w0.x);
                oacc.z += v0 * blo(w0.y); oacc.w += v0 * bhi(w0.y);
                oacc.x += v1 * blo(w1.x); oacc.y += v1 * bhi(w1.x);
                oacc.z += v1 * blo(w1.y); oacc.w += v1 * bhi(w1.y);
            }
        }
        for (; r < n; ++r) {
            uint2 dv = dec2[base + r];
            float v0 = __uint_as_float(dv.x);
            uint2 w0 = *(const uint2*)(wd + dv.y);
            oacc.x += v0 * blo(w0.x); oacc.y += v0 * bhi(w0.x);
            oacc.z += v0 * blo(w0.y); oacc.w += v0 * bhi(w0.y);
        }
        float l = 0.f;
        if (active) {
            *(float4*)&out_xdis[((size_t)k * NROWS + row) * DD + 4 * g] = oacc;
            float4 xv = *(const float4*)&xrow[4 * g];
            float4 yv = *(const float4*)&yr[4 * g];
            float e;
            e = oacc.x - xv.x; if (yv.x != 0.f) l += e * e;
            e = oacc.y - xv.y; if (yv.y != 0.f) l += e * e;
            e = oacc.z - xv.z; if (yv.z != 0.f) l += e * e;
            e = oacc.w - xv.w; if (yv.w != 0.f) l += e * e;
        }
        for (int o = 32; o; o >>= 1) l += __shfl_xor(l, o, 64);
        if (lane == 0) atomicAdd(&loss4[k], l);
    }
    __syncthreads();
    if (tid < NITER) lossp[row * NITER + tid] = loss4[tid];
}

// ---- finalize: losses[k] = sum_rows lossp / sum_rows ycnt ----
__global__ __launch_bounds__(256) void finalize2(
    const float* __restrict__ lossp, const int* __restrict__ ycnt,
    float* __restrict__ losses)
{
    const int tid = threadIdx.x, lane = tid & 63, w = tid >> 6;
    __shared__ int ctot[4];
    int c = ycnt[tid];
    for (int o = 32; o; o >>= 1) c += __shfl_xor(c, o, 64);
    if (lane == 0) ctot[w] = c;
    __syncthreads();
    const int total = ctot[0] + ctot[1] + ctot[2] + ctot[3];
    float s = lossp[lane * NITER + w] + lossp[(lane + 64) * NITER + w]
            + lossp[(lane + 128) * NITER + w] + lossp[(lane + 192) * NITER + w];
    for (int o = 32; o; o >>= 1) s += __shfl_xor(s, o, 64);
    if (lane == 0) losses[w] = s / (float)total;
}

extern "C" void kernel_launch(void* const* d_in, const int* in_sizes, int n_in,
                              void* d_out, int out_size, void* d_ws, size_t ws_size,
                              hipStream_t stream) {
    const float* x    = (const float*)d_in[0];
    const float* y    = (const float*)d_in[1];
    const float* Wenc = (const float*)d_in[2];
    const float* benc = (const float*)d_in[3];
    const float* Wdec = (const float*)d_in[4];
    const float* bdec = (const float*)d_in[5];

    float* out  = (float*)d_out;
    float* loss = out + (out_size - NITER);

    // workspace (all regions fully written before read each launch; 16B-aligned)
    float* lossp  = (float*)d_ws;                          // 1024 floats
    int*   ycnt   = (int*)(lossp + NROWS * NITER);         // 256 ints
    u32*   wenc16 = (u32*)(ycnt + NROWS);                  // 393216 u16 = 196608 u32
    u32*   wdec16 = wenc16 + (DD * HD) / 2;                // 393216 u16

    convert_kernel<<<256, 256, 0, stream>>>(Wenc, Wdec, (uint2*)wenc16, (uint2*)wdec16);
    fused_kernel<<<NROWS, 512, 0, stream>>>(x, y, wenc16, benc, wdec16, bdec,
                                            out, lossp, ycnt);
    finalize2<<<1, 256, 0, stream>>>(lossp, ycnt, loss);
}

// Round 13
// 109.757 us; speedup vs baseline: 1.0489x; 1.0137x over previous
//
#include <hip/hip_runtime.h>
#include <math.h>

#define DD 384
#define HD 1024
#define CD 256
#define NS 765        // 2*DD-1 shifts
#define NITER 4
#define NROWS 256     // B*T
#define TEMPER_F 10.0f
#define EPSF 1e-6f
#define CUTF 1e-10f

typedef unsigned long long u64;
typedef unsigned int u32;

// monotone float->uint (ascending)
__device__ __forceinline__ u32 flipf(float f) {
    u32 u = __float_as_uint(f);
    return u ^ ((u32)((int)u >> 31) | 0x80000000u);
}
// inverse, where s = ~flip(v)
__device__ __forceinline__ float unflipf(u32 s) {
    u32 fl = ~s;
    u32 u = (fl & 0x80000000u) ? (fl ^ 0x80000000u) : ~fl;
    return __uint_as_float(u);
}
__device__ __forceinline__ u64 shflx64(u64 v, int m) {
    int lo = __shfl_xor((int)(u32)v, m, 64);
    int hi = __shfl_xor((int)(u32)(v >> 32), m, 64);
    return ((u64)(u32)hi << 32) | (u32)lo;
}
// fp32 -> bf16 (RTNE), packed pair (lo element in low 16 bits)
__device__ __forceinline__ u32 bf16r(float f) {
    u32 u = __float_as_uint(f);
    return (u + 0x7FFFu + ((u >> 16) & 1u)) >> 16;
}
__device__ __forceinline__ u32 pack2(float a, float b) {
    return bf16r(a) | (bf16r(b) << 16);
}
__device__ __forceinline__ float blo(u32 p) { return __uint_as_float(p << 16); }
__device__ __forceinline__ float bhi(u32 p) { return __uint_as_float(p & 0xFFFF0000u); }

// ---- 0) convert weights to packed bf16 in d_ws ----
// Precision: h ~ N(0,2e-3); bf16 W perturbs h ~4e-6 abs; rank flips swap near-equal
// values (output effect ~2e-4 << 2e-2 threshold). sim/theta path stays fp32.
__global__ __launch_bounds__(256) void convert_kernel(
    const float* __restrict__ We, const float* __restrict__ Wd,
    uint2* __restrict__ we16, uint2* __restrict__ wd16)
{
    const int t = blockIdx.x * 256 + threadIdx.x;      // 65536 threads
    for (int i = t; i < (DD * HD) / 4; i += 65536) {
        float4 v = ((const float4*)We)[i];
        we16[i] = make_uint2(pack2(v.x, v.y), pack2(v.z, v.w));
    }
    for (int i = t; i < (HD * DD) / 4; i += 65536) {
        float4 v = ((const float4*)Wd)[i];
        wd16[i] = make_uint2(pack2(v.x, v.y), pack2(v.z, v.w));
    }
}

// One 1024-thread block per row: prep -> encoder(K-split 4) -> 1-elem register
// bitonic sort -> decode (2 cols/thread). 16 waves/CU for latency hiding.
__global__ __launch_bounds__(1024) void fused_kernel(
    const float* __restrict__ x, const float* __restrict__ y,
    const u32* __restrict__ wenc16, const float* __restrict__ benc,
    const u32* __restrict__ wdec16, const float* __restrict__ bdec,
    float* __restrict__ out_xdis, float* __restrict__ lossp,
    int* __restrict__ ycnt)
{
    const int row  = blockIdx.x;
    const int tid  = threadIdx.x;
    const int lane = tid & 63;
    const int wid  = tid >> 6;       // 0..15

    __shared__ __align__(16) float xpad[1152];    // xfull(t), zero-padded
    __shared__ __align__(16) float yr[DD];
    __shared__ float xa[DD];
    __shared__ __align__(16) float xe_s[DD];
    __shared__ __align__(16) float part[4][HD];   // encoder K-split partials (16KB)
    __shared__ __align__(16) u64   skey[HD];      // sort LDS rounds (j>=64) only
    __shared__ __align__(16) uint2 dec2[HD];      // {bits(v), idx*192 (u32 units)}
    __shared__ float wred[16];
    __shared__ int   wredi[16];
    __shared__ float wredn[16];
    __shared__ float s_sc[4];                     // qn, dn, mx, sum
    __shared__ int   s_theta, s_fb;
    __shared__ float loss4[NITER];

    const float* xrow = x + row * DD;
    const float* yrow = y + row * DD;

    // xfull(t) = x[t-383] for t in [383,767), else 0
    for (int i = tid; i < 1152; i += 1024)
        xpad[i] = (i >= DD - 1 && i < 2 * DD - 1) ? xrow[i - (DD - 1)] : 0.f;
    if (tid < DD) yr[tid] = yrow[tid];
    __syncthreads();

    // ---- qn = ||y||  (+ y-count folded in; waves 0..5) ----
    if (tid < DD) {
        float p = yr[tid] * yr[tid];
        int   c = (yr[tid] != 0.f) ? 1 : 0;
        for (int o = 32; o; o >>= 1) {
            p += __shfl_xor(p, o, 64);
            c += __shfl_xor(c, o, 64);
        }
        if (lane == 0) { wred[wid] = p; wredi[wid] = c; }
    }
    __syncthreads();
    if (tid == 0) {
        float s = 0.f; int c = 0;
        for (int w = 0; w < 6; ++w) { s += wred[w]; c += wredi[w]; }
        s_sc[0] = sqrtf(s);
        ycnt[row] = c;
    }
    __syncthreads();
    const float qn = s_sc[0];

    // ---- sim argmax: threads 0..191, 4 consecutive shifts each, sliding window ----
    float bv = -INFINITY; int bs = 0x7fffffff; float bn = 0.f;
    if (tid < 192) {
        const float4* xp4 = (const float4*)xpad;
        const float4* yp4 = (const float4*)yr;
        float4 A = xp4[tid];
        const float f0 = A.x * A.x, f1 = A.y * A.y, f2 = A.z * A.z;
        float d0 = 0.f, d1 = 0.f, d2 = 0.f, d3 = 0.f, n0 = 0.f;
#pragma unroll 4
        for (int jc = 0; jc < 96; ++jc) {
            float4 B = xp4[tid + jc + 1];
            float4 Y = yp4[jc];
            d0 += A.x * Y.x; d0 += A.y * Y.y; d0 += A.z * Y.z; d0 += A.w * Y.w;
            d1 += A.y * Y.x; d1 += A.z * Y.y; d1 += A.w * Y.z; d1 += B.x * Y.w;
            d2 += A.z * Y.x; d2 += A.w * Y.y; d2 += B.x * Y.z; d2 += B.y * Y.w;
            d3 += A.w * Y.x; d3 += B.x * Y.y; d3 += B.y * Y.z; d3 += B.z * Y.w;
            n0 += A.x * A.x; n0 += A.y * A.y; n0 += A.z * A.z; n0 += A.w * A.w;
            A = B;
        }
        const float n1 = n0 - f0 + A.x * A.x;
        const float n2 = n1 - f1 + A.y * A.y;
        const float n3 = n2 - f2 + A.z * A.z;
        const int s0 = 4 * tid;
        float sim0 = d0 / (qn * sqrtf(n0) + EPSF);
        float sim1 = d1 / (qn * sqrtf(n1) + EPSF);
        float sim2 = d2 / (qn * sqrtf(n2) + EPSF);
        float sim3 = d3 / (qn * sqrtf(n3) + EPSF);
        bv = sim0; bs = s0; bn = n0;
        if (s0 + 1 < NS && sim1 > bv) { bv = sim1; bs = s0 + 1; bn = n1; }
        if (s0 + 2 < NS && sim2 > bv) { bv = sim2; bs = s0 + 2; bn = n2; }
        if (s0 + 3 < NS && sim3 > bv) { bv = sim3; bs = s0 + 3; bn = n3; }
    }
    for (int o = 32; o; o >>= 1) {
        float v2 = __shfl_xor(bv, o, 64);
        int   i2 = __shfl_xor(bs, o, 64);
        float n2 = __shfl_xor(bn, o, 64);
        if (v2 > bv || (v2 == bv && i2 < bs)) { bv = v2; bs = i2; bn = n2; }
    }
    if (lane == 0) { wred[wid] = bv; wredi[wid] = bs; wredn[wid] = bn; }
    __syncthreads();
    if (tid == 0) {
        float v = wred[0]; int b = wredi[0]; float nn = wredn[0];
        for (int w = 1; w < 16; ++w)
            if (wred[w] > v || (wred[w] == v && wredi[w] < b)) {
                v = wred[w]; b = wredi[w]; nn = wredn[w];
            }
        s_theta = b;
        s_sc[1] = sqrtf(nn) * qn + EPSF;      // dn from carried nrm(theta)
    }
    __syncthreads();
    const int theta = s_theta;
    const float dn = s_sc[1];

    // ---- softmax((x_opt*y/dn)/T); x_attn (waves 0..5) ----
    float xo = 0.f, z = 0.f;
    if (tid < DD) {
        xo = xpad[theta + tid];
        z = (xo * yr[tid] / dn) / TEMPER_F;
        float m = z;
        for (int o = 32; o; o >>= 1) { float w2 = __shfl_xor(m, o, 64); if (w2 > m) m = w2; }
        if (lane == 0) wred[wid] = m;
    }
    __syncthreads();
    if (tid == 0) {
        float m = wred[0];
        for (int w = 1; w < 6; ++w) if (wred[w] > m) m = wred[w];
        s_sc[2] = m;
    }
    __syncthreads();
    float ez = 0.f;
    if (tid < DD) {
        ez = expf(z - s_sc[2]);
        float p = ez;
        for (int o = 32; o; o >>= 1) p += __shfl_xor(p, o, 64);
        if (lane == 0) wred[wid] = p;
    }
    __syncthreads();
    if (tid == 0) {
        float s = 0.f;
        for (int w = 0; w < 6; ++w) s += wred[w];
        s_sc[3] = s;
    }
    __syncthreads();
    if (tid < DD) xa[tid] = xo * (ez / s_sc[3]);
    __syncthreads();
    if (tid < DD) {
        int sj = tid - (theta - (DD - 1));
        xe_s[tid] = (sj >= 0 && sj < DD) ? xa[sj] : 0.f;
    }
    __syncthreads();

    // ---- encoder: K-split 4x on bf16 Wenc. quarter ks does K rows [96ks, 96ks+96)
    //      for its 4 cols; per-column reduce -> h in register -> sort key ----
    {
        const int ks = tid >> 8;              // 0..3
        const int c4 = tid & 255;             // col quad
        const u32* wbase = wenc16 + (size_t)(ks * 96) * 512 + 2 * c4;  // u32 units
        const float* xb = xe_s + ks * 96;
        float4 acc = make_float4(0.f, 0.f, 0.f, 0.f);
#pragma unroll 8
        for (int j = 0; j < 96; ++j) {
            float xv = xb[j];                 // broadcast
            uint2 wv = *(const uint2*)(wbase + (size_t)j * 512);
            acc.x += xv * blo(wv.x); acc.y += xv * bhi(wv.x);
            acc.z += xv * blo(wv.y); acc.w += xv * bhi(wv.y);
        }
        *(float4*)&part[ks][4 * c4] = acc;
    }
    if (tid == 0) s_fb = HD;
    if (tid < NITER) loss4[tid] = 0.f;
    __syncthreads();

    u64 e;
    {
        float hv = part[0][tid] + part[1][tid] + part[2][tid] + part[3][tid]
                 + benc[tid];
        e = ((u64)(~flipf(hv)) << 32) | (u32)tid;
    }

    // ---- register bitonic sort: 1 element/thread; ascending u64 == (desc h, asc idx) ----
    for (int k = 2; k <= HD; k <<= 1) {
        const bool up = (tid & k) == 0;
        for (int j = k >> 1; j > 0; j >>= 1) {
            if (j <= 32) {
                u64 p = shflx64(e, j);
                const bool takeMin = ((tid & j) == 0) == up;
                e = takeMin ? (e < p ? e : p) : (e > p ? e : p);
            } else {                           // j in {64,128,256,512}: via LDS
                __syncthreads();               // WAR protection
                skey[tid] = e;
                __syncthreads();
                u64 p = skey[tid ^ j];
                const bool takeMin = ((tid & j) == 0) == up;
                e = takeMin ? (e < p ? e : p) : (e > p ? e : p);
            }
        }
    }

    // ---- unpack + first position with v <= CUTF ----
    {
        float v = unflipf((u32)(e >> 32));
        dec2[tid] = make_uint2(__float_as_uint(v), ((u32)e) * 192);
        int fbloc = (v > CUTF) ? HD : tid;
        for (int o = 32; o; o >>= 1) { int t2 = __shfl_xor(fbloc, o, 64); if (t2 < fbloc) fbloc = t2; }
        if (lane == 0) atomicMin(&s_fb, fbloc);
    }
    __syncthreads();
    const int fb = s_fb;

    // ---- decode: 4 groups of 256 threads (k wave-uniform), 2 cols/thread,
    //      bf16 Wdec gather (4B/lane), unroll 8 ----
    {
        const int k = tid >> 8;
        const int g = tid & 255;
        const bool active = (g < 192);        // 192 col-pairs = 384 cols
        int n = 0;
        if (active) {
            n = (k == 0) ? CD : fb - k * CD;
            if (n < 0) n = 0; if (n > CD) n = CD;
        }
        float2 oacc = make_float2(0.f, 0.f);
        if (active) oacc = *(const float2*)&bdec[2 * g];
        const u32* wd = wdec16 + g;           // u32 units; row = idx*192
        const int base = k * CD;
        int r = 0;
        for (; r + 8 <= n; r += 8) {
#pragma unroll
            for (int q = 0; q < 8; q += 2) {
                uint4 dv = *(const uint4*)&dec2[base + r + q];   // 2 entries
                float v0 = __uint_as_float(dv.x);
                u32 w0 = wd[dv.y];
                float v1 = __uint_as_float(dv.z);
                u32 w1 = wd[dv.w];
                oacc.x += v0 * blo(w0); oacc.y += v0 * bhi(w0);
                oacc.x += v1 * blo(w1); oacc.y += v1 * bhi(w1);
            }
        }
        for (; r < n; ++r) {
            uint2 dv = dec2[base + r];
            float v0 = __uint_as_float(dv.x);
            u32 w0 = wd[dv.y];
            oacc.x += v0 * blo(w0); oacc.y += v0 * bhi(w0);
        }
        float l = 0.f;
        if (active) {
            *(float2*)&out_xdis[((size_t)k * NROWS + row) * DD + 2 * g] = oacc;
            float2 xv = *(const float2*)&xrow[2 * g];
            float2 yv = *(const float2*)&yr[2 * g];
            float ee;
            ee = oacc.x - xv.x; if (yv.x != 0.f) l += ee * ee;
            ee = oacc.y - xv.y; if (yv.y != 0.f) l += ee * ee;
        }
        for (int o = 32; o; o >>= 1) l += __shfl_xor(l, o, 64);
        if (lane == 0) atomicAdd(&loss4[k], l);
    }
    __syncthreads();
    if (tid < NITER) lossp[row * NITER + tid] = loss4[tid];
}

// ---- finalize: losses[k] = sum_rows lossp / sum_rows ycnt ----
__global__ __launch_bounds__(256) void finalize2(
    const float* __restrict__ lossp, const int* __restrict__ ycnt,
    float* __restrict__ losses)
{
    const int tid = threadIdx.x, lane = tid & 63, w = tid >> 6;
    __shared__ int ctot[4];
    int c = ycnt[tid];
    for (int o = 32; o; o >>= 1) c += __shfl_xor(c, o, 64);
    if (lane == 0) ctot[w] = c;
    __syncthreads();
    const int total = ctot[0] + ctot[1] + ctot[2] + ctot[3];
    float s = lossp[lane * NITER + w] + lossp[(lane + 64) * NITER + w]
            + lossp[(lane + 128) * NITER + w] + lossp[(lane + 192) * NITER + w];
    for (int o = 32; o; o >>= 1) s += __shfl_xor(s, o, 64);
    if (lane == 0) losses[w] = s / (float)total;
}

extern "C" void kernel_launch(void* const* d_in, const int* in_sizes, int n_in,
                              void* d_out, int out_size, void* d_ws, size_t ws_size,
                              hipStream_t stream) {
    const float* x    = (const float*)d_in[0];
    const float* y    = (const float*)d_in[1];
    const float* Wenc = (const float*)d_in[2];
    const float* benc = (const float*)d_in[3];
    const float* Wdec = (const float*)d_in[4];
    const float* bdec = (const float*)d_in[5];

    float* out  = (float*)d_out;
    float* loss = out + (out_size - NITER);

    // workspace (all regions fully written before read each launch; 16B-aligned)
    float* lossp  = (float*)d_ws;                          // 1024 floats
    int*   ycnt   = (int*)(lossp + NROWS * NITER);         // 256 ints
    u32*   wenc16 = (u32*)(ycnt + NROWS);                  // 196608 u32
    u32*   wdec16 = wenc16 + (DD * HD) / 2;                // 196608 u32

    convert_kernel<<<256, 256, 0, stream>>>(Wenc, Wdec, (uint2*)wenc16, (uint2*)wdec16);
    fused_kernel<<<NROWS, 1024, 0, stream>>>(x, y, wenc16, benc, wdec16, bdec,
                                             out, lossp, ycnt);
    finalize2<<<1, 256, 0, stream>>>(lossp, ycnt, loss);
}

// Round 14
// 106.184 us; speedup vs baseline: 1.0842x; 1.0337x over previous
//
#include <hip/hip_runtime.h>
#include <hip/hip_fp16.h>
#include <math.h>

#define DD 384
#define HD 1024
#define CD 256
#define NS 765        // 2*DD-1 shifts
#define NITER 4
#define NROWS 256     // B*T
#define TEMPER_F 10.0f
#define EPSF 1e-6f
#define CUTF 1e-10f

typedef unsigned long long u64;
typedef unsigned int u32;
typedef _Float16 hh2 __attribute__((ext_vector_type(2)));

// monotone float->uint (ascending)
__device__ __forceinline__ u32 flipf(float f) {
    u32 u = __float_as_uint(f);
    return u ^ ((u32)((int)u >> 31) | 0x80000000u);
}
// fp32 -> bf16 (RTNE), packed pair
__device__ __forceinline__ u32 bf16r(float f) {
    u32 u = __float_as_uint(f);
    return (u + 0x7FFFu + ((u >> 16) & 1u)) >> 16;
}
__device__ __forceinline__ u32 pack2bf(float a, float b) {
    return bf16r(a) | (bf16r(b) << 16);
}
__device__ __forceinline__ float blo(u32 p) { return __uint_as_float(p << 16); }
__device__ __forceinline__ float bhi(u32 p) { return __uint_as_float(p & 0xFFFF0000u); }
// fp32 pair -> packed f16 (RTNE)
__device__ __forceinline__ u32 packh2(float a, float b) {
    __half2 p = __floats2half2_rn(a, b);
    return __builtin_bit_cast(u32, p);
}
// fp32 += dot2(f16x2, f16x2)
__device__ __forceinline__ float dot2(u32 a, u32 b, float c) {
#if __has_builtin(__builtin_amdgcn_fdot2)
    return __builtin_amdgcn_fdot2(__builtin_bit_cast(hh2, a),
                                  __builtin_bit_cast(hh2, b), c, false);
#else
    __half2 ah = __builtin_bit_cast(__half2, a);
    __half2 bh = __builtin_bit_cast(__half2, b);
    return fmaf(__half2float(ah.y), __half2float(bh.y),
           fmaf(__half2float(ah.x), __half2float(bh.x), c));
#endif
}

// ---- 0) convert weights: Wenc -> f16 K-paired [192][1024] u32;
//         Wdec -> bf16 col-paired [1024][192] u32 ----
__global__ __launch_bounds__(256) void convert_kernel(
    const float* __restrict__ We, const float* __restrict__ Wd,
    u32* __restrict__ wencp, uint2* __restrict__ wd16)
{
    const int t = blockIdx.x * 256 + threadIdx.x;      // 65536 threads
    for (int i = t; i < 192 * HD; i += 65536) {        // 3 iters
        int j2 = i >> 10, c = i & 1023;
        wencp[i] = packh2(We[(2 * j2) * HD + c], We[(2 * j2 + 1) * HD + c]);
    }
    for (int i = t; i < (HD * DD) / 4; i += 65536) {
        float4 v = ((const float4*)Wd)[i];
        wd16[i] = make_uint2(pack2bf(v.x, v.y), pack2bf(v.z, v.w));
    }
}

// One 1024-thread block per row: prep -> fdot2 encoder -> u32-key bitonic sort
// (boundaries only) -> ballot-compaction partition -> decode.
__global__ __launch_bounds__(1024) void fused_kernel(
    const float* __restrict__ x, const float* __restrict__ y,
    const u32* __restrict__ wencp, const float* __restrict__ benc,
    const u32* __restrict__ wdec16, const float* __restrict__ bdec,
    float* __restrict__ out_xdis, float* __restrict__ lossp,
    int* __restrict__ ycnt)
{
    const int row  = blockIdx.x;
    const int tid  = threadIdx.x;
    const int lane = tid & 63;
    const int wid  = tid >> 6;       // 0..15

    __shared__ __align__(16) float xpad[1152];
    __shared__ __align__(16) float yr[DD];
    __shared__ float xa[DD];
    __shared__ __align__(16) float xe_s[DD];
    __shared__ u32   xep[192];                    // xe packed f16 pairs
    __shared__ __align__(16) float part[4][HD];   // encoder K-split partials
    __shared__ u32   sk0[HD], sk1[HD];            // sort dbuf (u32 keys)
    __shared__ __align__(16) uint2 dec2[HD];      // {bits(v), idx*192}
    __shared__ float wred[16];
    __shared__ int   wredi[16];
    __shared__ float wredn[16];
    __shared__ float s_sc[4];
    __shared__ int   s_theta;
    __shared__ u32   s_b1, s_b2, s_b3;
    __shared__ int   wcls[128];                   // per (class, wave) counts
    __shared__ int   sbase[128];                  // exclusive scan
    __shared__ int   cnt8[8];
    __shared__ float loss4[NITER];

    const float* xrow = x + row * DD;
    const float* yrow = y + row * DD;

    for (int i = tid; i < 1152; i += 1024)
        xpad[i] = (i >= DD - 1 && i < 2 * DD - 1) ? xrow[i - (DD - 1)] : 0.f;
    if (tid < DD) yr[tid] = yrow[tid];
    __syncthreads();

    // ---- qn = ||y|| (+ y-count) ----
    if (tid < DD) {
        float p = yr[tid] * yr[tid];
        int   c = (yr[tid] != 0.f) ? 1 : 0;
        for (int o = 32; o; o >>= 1) {
            p += __shfl_xor(p, o, 64);
            c += __shfl_xor(c, o, 64);
        }
        if (lane == 0) { wred[wid] = p; wredi[wid] = c; }
    }
    __syncthreads();
    if (tid == 0) {
        float s = 0.f; int c = 0;
        for (int w = 0; w < 6; ++w) { s += wred[w]; c += wredi[w]; }
        s_sc[0] = sqrtf(s);
        ycnt[row] = c;
    }
    __syncthreads();
    const float qn = s_sc[0];

    // ---- sim argmax: threads 0..191, 4 consecutive shifts, sliding window ----
    float bv = -INFINITY; int bs = 0x7fffffff; float bn = 0.f;
    if (tid < 192) {
        const float4* xp4 = (const float4*)xpad;
        const float4* yp4 = (const float4*)yr;
        float4 A = xp4[tid];
        const float f0 = A.x * A.x, f1 = A.y * A.y, f2 = A.z * A.z;
        float d0 = 0.f, d1 = 0.f, d2 = 0.f, d3 = 0.f, n0 = 0.f;
#pragma unroll 4
        for (int jc = 0; jc < 96; ++jc) {
            float4 B = xp4[tid + jc + 1];
            float4 Y = yp4[jc];
            d0 += A.x * Y.x; d0 += A.y * Y.y; d0 += A.z * Y.z; d0 += A.w * Y.w;
            d1 += A.y * Y.x; d1 += A.z * Y.y; d1 += A.w * Y.z; d1 += B.x * Y.w;
            d2 += A.z * Y.x; d2 += A.w * Y.y; d2 += B.x * Y.z; d2 += B.y * Y.w;
            d3 += A.w * Y.x; d3 += B.x * Y.y; d3 += B.y * Y.z; d3 += B.z * Y.w;
            n0 += A.x * A.x; n0 += A.y * A.y; n0 += A.z * A.z; n0 += A.w * A.w;
            A = B;
        }
        const float n1 = n0 - f0 + A.x * A.x;
        const float n2 = n1 - f1 + A.y * A.y;
        const float n3 = n2 - f2 + A.z * A.z;
        const int s0 = 4 * tid;
        float sim0 = d0 / (qn * sqrtf(n0) + EPSF);
        float sim1 = d1 / (qn * sqrtf(n1) + EPSF);
        float sim2 = d2 / (qn * sqrtf(n2) + EPSF);
        float sim3 = d3 / (qn * sqrtf(n3) + EPSF);
        bv = sim0; bs = s0; bn = n0;
        if (s0 + 1 < NS && sim1 > bv) { bv = sim1; bs = s0 + 1; bn = n1; }
        if (s0 + 2 < NS && sim2 > bv) { bv = sim2; bs = s0 + 2; bn = n2; }
        if (s0 + 3 < NS && sim3 > bv) { bv = sim3; bs = s0 + 3; bn = n3; }
    }
    for (int o = 32; o; o >>= 1) {
        float v2 = __shfl_xor(bv, o, 64);
        int   i2 = __shfl_xor(bs, o, 64);
        float n2 = __shfl_xor(bn, o, 64);
        if (v2 > bv || (v2 == bv && i2 < bs)) { bv = v2; bs = i2; bn = n2; }
    }
    if (lane == 0) { wred[wid] = bv; wredi[wid] = bs; wredn[wid] = bn; }
    __syncthreads();
    if (tid == 0) {
        float v = wred[0]; int b = wredi[0]; float nn = wredn[0];
        for (int w = 1; w < 16; ++w)
            if (wred[w] > v || (wred[w] == v && wredi[w] < b)) {
                v = wred[w]; b = wredi[w]; nn = wredn[w];
            }
        s_theta = b;
        s_sc[1] = sqrtf(nn) * qn + EPSF;      // dn from carried nrm(theta)
    }
    __syncthreads();
    const int theta = s_theta;
    const float dn = s_sc[1];

    // ---- softmax without max-pass (|z| <= 0.1 by Cauchy-Schwarz) ----
    float xo = 0.f, ez = 0.f;
    if (tid < DD) {
        xo = xpad[theta + tid];
        ez = expf((xo * yr[tid] / dn) / TEMPER_F);
        float p = ez;
        for (int o = 32; o; o >>= 1) p += __shfl_xor(p, o, 64);
        if (lane == 0) wred[wid] = p;
    }
    __syncthreads();
    if (tid == 0) {
        float s = 0.f;
        for (int w = 0; w < 6; ++w) s += wred[w];
        s_sc[3] = s;
    }
    __syncthreads();
    if (tid < DD) xa[tid] = xo * (ez / s_sc[3]);
    __syncthreads();
    if (tid < DD) {
        int sj = tid - (theta - (DD - 1));
        xe_s[tid] = (sj >= 0 && sj < DD) ? xa[sj] : 0.f;
    }
    __syncthreads();
    if (tid < 192) xep[tid] = packh2(xe_s[2 * tid], xe_s[2 * tid + 1]);
    __syncthreads();

    // ---- encoder: K-split 4x, f16 pairs, fdot2. quarter ks: K-pairs [48ks,48ks+48) ----
    {
        const int ks = tid >> 8;              // 0..3 (wave-uniform)
        const int c4 = tid & 255;             // col quad: cols 4c4..4c4+3
        const uint4* wq = (const uint4*)wencp + (size_t)(ks * 48) * 256 + c4;
        const u32* xb = xep + ks * 48;
        float4 acc = make_float4(0.f, 0.f, 0.f, 0.f);
#pragma unroll 8
        for (int j2 = 0; j2 < 48; ++j2) {
            u32 xv = xb[j2];                  // broadcast
            uint4 w = wq[(size_t)j2 * 256];
            acc.x = dot2(xv, w.x, acc.x);
            acc.y = dot2(xv, w.y, acc.y);
            acc.z = dot2(xv, w.z, acc.z);
            acc.w = dot2(xv, w.w, acc.w);
        }
        *(float4*)&part[ks][4 * c4] = acc;
    }
    if (tid < 8) cnt8[tid] = 0;
    if (tid < NITER) loss4[tid] = 0.f;
    __syncthreads();

    float oh;
    u32 okey, e;
    {
        oh = part[0][tid] + part[1][tid] + part[2][tid] + part[3][tid] + benc[tid];
        okey = ~flipf(oh);                    // ascending key == descending h
        e = okey;
    }

    // ---- bitonic sort of bare u32 keys (1/thread); dbuf LDS rounds ----
    int par = 0;
    for (int k = 2; k <= HD; k <<= 1) {
        const bool up = (tid & k) == 0;
        for (int j = k >> 1; j > 0; j >>= 1) {
            if (j <= 32) {
                u32 p = __shfl_xor(e, j, 64);
                const bool takeMin = ((tid & j) == 0) == up;
                e = takeMin ? (e < p ? e : p) : (e > p ? e : p);
            } else {                           // j in {64,128,256,512}
                u32* buf = par ? sk1 : sk0; par ^= 1;
                buf[tid] = e;
                __syncthreads();
                u32 p = buf[tid ^ j];
                const bool takeMin = ((tid & j) == 0) == up;
                e = takeMin ? (e < p ? e : p) : (e > p ? e : p);
            }
        }
    }
    // boundary keys at ranks 255/511/767
    if (tid == 255) s_b1 = e;
    if (tid == 511) s_b2 = e;
    if (tid == 767) s_b3 = e;
    __syncthreads();
    const u32 b1 = s_b1, b2 = s_b2, b3 = s_b3;

    // ---- partition: class = 2*quartile + (below-cutoff); ballot compaction ----
    {
        const int myk = (okey <= b1) ? 0 : (okey <= b2) ? 1 : (okey <= b3) ? 2 : 3;
        const int cls = 2 * myk + ((oh > CUTF) ? 0 : 1);
        int myprefix = 0;
        const u64 ltmask = (1ull << lane) - 1;
#pragma unroll
        for (int c = 0; c < 8; ++c) {
            u64 m = __ballot(cls == c);
            if (cls == c) myprefix = __popcll(m & ltmask);
            if (lane == 0) {
                wcls[c * 16 + wid] = (int)__popcll(m);
                atomicAdd(&cnt8[c], (int)__popcll(m));
            }
        }
        __syncthreads();
        if (tid < 128) {
            int v = wcls[tid];
            int inc = v;
            for (int o = 1; o < 64; o <<= 1) {
                int t2 = __shfl_up(inc, o, 64);
                if (lane >= o) inc += t2;
            }
            sbase[tid] = inc - v;             // wave-local exclusive
        }
        __syncthreads();
        if (tid >= 64 && tid < 128) sbase[tid] += sbase[63] + wcls[63];
        __syncthreads();
        const int slot = sbase[cls * 16 + wid] + myprefix;
        dec2[slot] = make_uint2(__float_as_uint(oh), (u32)tid * 192u);
    }
    __syncthreads();

    // ---- decode: 4 groups of 256 threads (k wave-uniform), 2 cols/thread ----
    {
        const int k = tid >> 8;
        const int g = tid & 255;
        const bool active = (g < 192);
        int n = 0;
        if (active) n = (k == 0) ? CD : cnt8[2 * k];
        float2 oacc = make_float2(0.f, 0.f);
        if (active) oacc = *(const float2*)&bdec[2 * g];
        const u32* wd = wdec16 + g;
        const int base = k * CD;
        int r = 0;
        for (; r + 8 <= n; r += 8) {
#pragma unroll
            for (int q = 0; q < 8; q += 2) {
                uint4 dv = *(const uint4*)&dec2[base + r + q];
                float v0 = __uint_as_float(dv.x);
                u32 w0 = wd[dv.y];
                float v1 = __uint_as_float(dv.z);
                u32 w1 = wd[dv.w];
                oacc.x += v0 * blo(w0); oacc.y += v0 * bhi(w0);
                oacc.x += v1 * blo(w1); oacc.y += v1 * bhi(w1);
            }
        }
        for (; r < n; ++r) {
            uint2 dv = dec2[base + r];
            float v0 = __uint_as_float(dv.x);
            u32 w0 = wd[dv.y];
            oacc.x += v0 * blo(w0); oacc.y += v0 * bhi(w0);
        }
        float l = 0.f;
        if (active) {
            *(float2*)&out_xdis[((size_t)k * NROWS + row) * DD + 2 * g] = oacc;
            float2 xv = *(const float2*)&xrow[2 * g];
            float2 yv = *(const float2*)&yr[2 * g];
            float ee;
            ee = oacc.x - xv.x; if (yv.x != 0.f) l += ee * ee;
            ee = oacc.y - xv.y; if (yv.y != 0.f) l += ee * ee;
        }
        for (int o = 32; o; o >>= 1) l += __shfl_xor(l, o, 64);
        if (lane == 0) atomicAdd(&loss4[k], l);
    }
    __syncthreads();
    if (tid < NITER) lossp[row * NITER + tid] = loss4[tid];
}

// ---- finalize: losses[k] = sum_rows lossp / sum_rows ycnt ----
__global__ __launch_bounds__(256) void finalize2(
    const float* __restrict__ lossp, const int* __restrict__ ycnt,
    float* __restrict__ losses)
{
    const int tid = threadIdx.x, lane = tid & 63, w = tid >> 6;
    __shared__ int ctot[4];
    int c = ycnt[tid];
    for (int o = 32; o; o >>= 1) c += __shfl_xor(c, o, 64);
    if (lane == 0) ctot[w] = c;
    __syncthreads();
    const int total = ctot[0] + ctot[1] + ctot[2] + ctot[3];
    float s = lossp[lane * NITER + w] + lossp[(lane + 64) * NITER + w]
            + lossp[(lane + 128) * NITER + w] + lossp[(lane + 192) * NITER + w];
    for (int o = 32; o; o >>= 1) s += __shfl_xor(s, o, 64);
    if (lane == 0) losses[w] = s / (float)total;
}

extern "C" void kernel_launch(void* const* d_in, const int* in_sizes, int n_in,
                              void* d_out, int out_size, void* d_ws, size_t ws_size,
                              hipStream_t stream) {
    const float* x    = (const float*)d_in[0];
    const float* y    = (const float*)d_in[1];
    const float* Wenc = (const float*)d_in[2];
    const float* benc = (const float*)d_in[3];
    const float* Wdec = (const float*)d_in[4];
    const float* bdec = (const float*)d_in[5];

    float* out  = (float*)d_out;
    float* loss = out + (out_size - NITER);

    // workspace (all regions fully written before read each launch; 16B-aligned)
    float* lossp  = (float*)d_ws;                          // 1024 floats
    int*   ycnt   = (int*)(lossp + NROWS * NITER);         // 256 ints
    u32*   wencp  = (u32*)(ycnt + NROWS);                  // 196608 u32 (f16 K-pairs)
    u32*   wdec16 = wencp + 192 * HD;                      // 196608 u32 (bf16 col-pairs)

    convert_kernel<<<256, 256, 0, stream>>>(Wenc, Wdec, wencp, (uint2*)wdec16);
    fused_kernel<<<NROWS, 1024, 0, stream>>>(x, y, wencp, benc, wdec16, bdec,
                                             out, lossp, ycnt);
    finalize2<<<1, 256, 0, stream>>>(lossp, ycnt, loss);
}